// Round 2
// baseline (325.850 us; speedup 1.0000x reference)
//
#include <hip/hip_runtime.h>
#include <math.h>

#define MAX_SEQ   1024
#define NUM_HEADS 16
#define NUM_KV    4
#define HEAD_DIM  128
#define HIDDEN    2048
#define GROUPS    4
#define EPS       1e-6f
#define THETA     1000000.0f
#define SCALE     0.08838834764831845f  /* 1/sqrt(128) */
#define NSPLIT    8

// workspace layout (float offsets)
#define QBUF 0                    // 32*16*128 = 65536
#define KBUF 65536                // 32*4*128  = 16384
#define VBUF 81920                // 16384
#define PART 98304                // 1024 blocks * 4 heads * 130 = 532480
#define AOUT 630784               // 32*2048 = 65536

// ---------------- Kernel 1: QKV projection + RMSNorm + RoPE ----------------
__global__ __launch_bounds__(256) void qkv_kernel(
    const float* __restrict__ x, const float* __restrict__ position,
    const float* __restrict__ wq, const float* __restrict__ wk,
    const float* __restrict__ wv, const float* __restrict__ qnw,
    const float* __restrict__ knw, float* __restrict__ ws)
{
    __shared__ float xs[HIDDEN];
    __shared__ float rv[HEAD_DIM];
    __shared__ float snorm;
    const int blk = blockIdx.x;
    const int b = blk / 24, hid = blk % 24;
    const int tid = threadIdx.x, lane = tid & 63, wave = tid >> 6;

    const float4* xg = (const float4*)(x + (size_t)b * HIDDEN);
    ((float4*)xs)[tid]       = xg[tid];
    ((float4*)xs)[tid + 256] = xg[tid + 256];
    __syncthreads();

    const float* W;
    int type, hh;                       // 0=q, 1=k, 2=v
    if (hid < 16)      { type = 0; hh = hid;      W = wq + (size_t)hh * HEAD_DIM * HIDDEN; }
    else if (hid < 20) { type = 1; hh = hid - 16; W = wk + (size_t)hh * HEAD_DIM * HIDDEN; }
    else               { type = 2; hh = hid - 20; W = wv + (size_t)hh * HEAD_DIM * HIDDEN; }

    // wave handles rows [wave*32, wave*32+32), 4 rows concurrently:
    // 32 float4 loads in flight per lane, 4 independent shuffle chains.
    for (int g4 = 0; g4 < 8; ++g4) {
        const int r = wave * 32 + g4 * 4;
        const float4* wr0 = (const float4*)(W + (size_t)(r + 0) * HIDDEN);
        const float4* wr1 = (const float4*)(W + (size_t)(r + 1) * HIDDEN);
        const float4* wr2 = (const float4*)(W + (size_t)(r + 2) * HIDDEN);
        const float4* wr3 = (const float4*)(W + (size_t)(r + 3) * HIDDEN);
        float s0 = 0.f, s1 = 0.f, s2 = 0.f, s3 = 0.f;
        #pragma unroll
        for (int j = 0; j < 8; ++j) {
            const int idx = lane + 64 * j;
            float4 x4 = ((const float4*)xs)[idx];
            float4 a = wr0[idx], bb = wr1[idx], c = wr2[idx], d = wr3[idx];
            s0 += a.x  * x4.x + a.y  * x4.y + a.z  * x4.z + a.w  * x4.w;
            s1 += bb.x * x4.x + bb.y * x4.y + bb.z * x4.z + bb.w * x4.w;
            s2 += c.x  * x4.x + c.y  * x4.y + c.z  * x4.z + c.w  * x4.w;
            s3 += d.x  * x4.x + d.y  * x4.y + d.z  * x4.z + d.w  * x4.w;
        }
        #pragma unroll
        for (int off = 32; off; off >>= 1) {
            s0 += __shfl_xor(s0, off);
            s1 += __shfl_xor(s1, off);
            s2 += __shfl_xor(s2, off);
            s3 += __shfl_xor(s3, off);
        }
        if (lane == 0) { rv[r] = s0; rv[r + 1] = s1; rv[r + 2] = s2; rv[r + 3] = s3; }
    }
    __syncthreads();

    float* outp;
    if (type == 0)      outp = ws + QBUF + ((size_t)b * NUM_HEADS + hh) * HEAD_DIM;
    else if (type == 1) outp = ws + KBUF + ((size_t)b * NUM_KV + hh) * HEAD_DIM;
    else                outp = ws + VBUF + ((size_t)b * NUM_KV + hh) * HEAD_DIM;

    if (type == 2) {                    // v: no norm, no rope
        if (tid < HEAD_DIM) outp[tid] = rv[tid];
        return;
    }

    if (wave == 0) {
        float t2 = rv[lane] * rv[lane] + rv[lane + 64] * rv[lane + 64];
        #pragma unroll
        for (int off = 32; off; off >>= 1) t2 += __shfl_xor(t2, off);
        if (lane == 0) snorm = rsqrtf(t2 * (1.0f / HEAD_DIM) + EPS);
    }
    __syncthreads();

    const float* nw = (type == 0) ? qnw : knw;
    if (tid < 64) {
        const float p = position[0];
        const float norm = snorm;
        float n1 = rv[tid]      * norm * nw[tid];
        float n2 = rv[tid + 64] * norm * nw[tid + 64];
        float invf = __powf(THETA, -(float)tid * (1.0f / 64.0f));
        float f = p * invf;
        float s, c;
        __sincosf(f, &s, &c);
        outp[tid]      = n1 * c - n2 * s;
        outp[tid + 64] = n2 * c + n1 * s;
    }
}

// ---------------- Kernel 2: flash-decode attention (split over seq) --------
// Each wave: 2 positions per step (half-wave per position, float4 loads),
// 2 position-pairs in flight per iteration.
__global__ __launch_bounds__(256) void attn_kernel(
    const float* __restrict__ kcache, const float* __restrict__ vcache,
    const float* __restrict__ position, float* __restrict__ ws)
{
    const int blk = blockIdx.x;         // (b*4+kv)*NSPLIT + split
    const int split = blk & (NSPLIT - 1);
    const int bk = blk >> 3;            // b*4+kv
    const int tid = threadIdx.x, lane = tid & 63, wave = tid >> 6;
    const int half = lane >> 5, li = lane & 31;
    const int b = bk >> 2, kv = bk & 3;
    const int pos = (int)position[0];

    const int chunk = (pos + NSPLIT) / NSPLIT;       // ceil((pos+1)/NSPLIT)
    const int s0 = split * chunk;
    const int s1 = min(s0 + chunk, pos + 1);

    const float* qb = ws + QBUF + ((size_t)b * NUM_HEADS + kv * GROUPS) * HEAD_DIM;
    float4 q4[4];
    #pragma unroll
    for (int g = 0; g < 4; ++g)
        q4[g] = ((const float4*)(qb + g * HEAD_DIM))[li];

    const float* kc = kcache + (size_t)bk * MAX_SEQ * HEAD_DIM;
    const float* vc = vcache + (size_t)bk * MAX_SEQ * HEAD_DIM;
    const float* knew = ws + KBUF + (size_t)bk * HEAD_DIM;
    const float* vnew = ws + VBUF + (size_t)bk * HEAD_DIM;

    float m[4], l[4]; float4 acc[4];
    #pragma unroll
    for (int g = 0; g < 4; ++g) {
        m[g] = -1e30f; l[g] = 0.f;
        acc[g] = make_float4(0.f, 0.f, 0.f, 0.f);
    }

    for (int t = s0 + wave * 2 + half; t < s1; t += 16) {
        const int tb = t + 8;
        const bool vb = (tb < s1);
        const int tbc = vb ? tb : t;
        const float4* kpa = (const float4*)((t   == pos) ? knew : kc + (size_t)t   * HEAD_DIM);
        const float4* kpb = (const float4*)((tbc == pos) ? knew : kc + (size_t)tbc * HEAD_DIM);
        const float4* vpa = (const float4*)((t   == pos) ? vnew : vc + (size_t)t   * HEAD_DIM);
        const float4* vpb = (const float4*)((tbc == pos) ? vnew : vc + (size_t)tbc * HEAD_DIM);
        float4 ka = kpa[li], kb = kpb[li];
        float4 va = vpa[li], vb4 = vpb[li];

        float sa[4], sb[4];
        #pragma unroll
        for (int g = 0; g < 4; ++g) {
            sa[g] = q4[g].x * ka.x + q4[g].y * ka.y + q4[g].z * ka.z + q4[g].w * ka.w;
            sb[g] = q4[g].x * kb.x + q4[g].y * kb.y + q4[g].z * kb.z + q4[g].w * kb.w;
        }
        #pragma unroll
        for (int off = 16; off; off >>= 1) {
            #pragma unroll
            for (int g = 0; g < 4; ++g) {
                sa[g] += __shfl_xor(sa[g], off);
                sb[g] += __shfl_xor(sb[g], off);
            }
        }
        #pragma unroll
        for (int g = 0; g < 4; ++g) {
            float sga = sa[g] * SCALE;
            float sgb = vb ? sb[g] * SCALE : -1e30f;
            float mn  = fmaxf(m[g], fmaxf(sga, sgb));
            float alpha = __expf(m[g] - mn);
            float pa = __expf(sga - mn);
            float pb = vb ? __expf(sgb - mn) : 0.f;
            l[g] = l[g] * alpha + pa + pb;
            acc[g].x = acc[g].x * alpha + pa * va.x + pb * vb4.x;
            acc[g].y = acc[g].y * alpha + pa * va.y + pb * vb4.y;
            acc[g].z = acc[g].z * alpha + pa * va.z + pb * vb4.z;
            acc[g].w = acc[g].w * alpha + pa * va.w + pb * vb4.w;
            m[g] = mn;
        }
    }

    // combine 8 streams (4 waves x 2 halves)
    __shared__ float sm[8][4], sl[8][4];
    __shared__ float4 sacc[8][4][32];
    const int st = wave * 2 + half;
    #pragma unroll
    for (int g = 0; g < 4; ++g) {
        if (li == 0) { sm[st][g] = m[g]; sl[st][g] = l[g]; }
        sacc[st][g][li] = acc[g];
    }
    __syncthreads();

    float* part = ws + PART + (size_t)blk * 4 * 130;
    if (tid < HEAD_DIM) {
        const int d = tid;
        #pragma unroll
        for (int g = 0; g < 4; ++g) {
            float M = -1e30f;
            #pragma unroll
            for (int s = 0; s < 8; ++s) M = fmaxf(M, sm[s][g]);
            float L = 0.f, A = 0.f;
            #pragma unroll
            for (int s = 0; s < 8; ++s) {
                float e = __expf(sm[s][g] - M);
                L += sl[s][g] * e;
                A += ((const float*)&sacc[s][g][0])[d] * e;
            }
            part[g * 130 + d] = A;
            if (d == 0) { part[g * 130 + 128] = M; part[g * 130 + 129] = L; }
        }
    }
}

// ---------------- Kernel 3: combine split partials -> attn_out -------------
__global__ __launch_bounds__(128) void comb_kernel(float* __restrict__ ws)
{
    const int blk = blockIdx.x;         // b*16 + h
    const int b = blk >> 4, h = blk & 15;
    const int kv = h >> 2, g = h & 3;
    const int d = threadIdx.x;
    const float* base = ws + PART + ((size_t)(b * NUM_KV + kv) * NSPLIT) * 4 * 130 + g * 130;

    float ms[NSPLIT], ls[NSPLIT];
    float M = -1e30f;
    #pragma unroll
    for (int s = 0; s < NSPLIT; ++s) {
        ms[s] = base[s * 520 + 128];
        ls[s] = base[s * 520 + 129];
        M = fmaxf(M, ms[s]);
    }
    float L = 0.f, A = 0.f;
    #pragma unroll
    for (int s = 0; s < NSPLIT; ++s) {
        float e = __expf(ms[s] - M);
        L += ls[s] * e;
        A += base[s * 520 + d] * e;
    }
    ws[AOUT + (size_t)b * HIDDEN + h * HEAD_DIM + d] = A / L;
}

// ---------------- Kernel 4: output projection ------------------------------
__global__ __launch_bounds__(256) void wo_kernel(
    const float* __restrict__ wo, const float* __restrict__ ws,
    float* __restrict__ out)
{
    __shared__ float xs[HIDDEN];
    const int blk = blockIdx.x;         // b*16 + chunk
    const int b = blk >> 4, chunk = blk & 15;
    const int tid = threadIdx.x, lane = tid & 63, wave = tid >> 6;

    const float4* xg = (const float4*)(ws + AOUT + (size_t)b * HIDDEN);
    ((float4*)xs)[tid]       = xg[tid];
    ((float4*)xs)[tid + 256] = xg[tid + 256];
    __syncthreads();

    const int r0 = chunk * 128;
    for (int g4 = 0; g4 < 8; ++g4) {
        const int r = wave * 32 + g4 * 4;
        const float4* wr0 = (const float4*)(wo + (size_t)(r0 + r + 0) * HIDDEN);
        const float4* wr1 = (const float4*)(wo + (size_t)(r0 + r + 1) * HIDDEN);
        const float4* wr2 = (const float4*)(wo + (size_t)(r0 + r + 2) * HIDDEN);
        const float4* wr3 = (const float4*)(wo + (size_t)(r0 + r + 3) * HIDDEN);
        float s0 = 0.f, s1 = 0.f, s2 = 0.f, s3 = 0.f;
        #pragma unroll
        for (int j = 0; j < 8; ++j) {
            const int idx = lane + 64 * j;
            float4 x4 = ((const float4*)xs)[idx];
            float4 a = wr0[idx], bb = wr1[idx], c = wr2[idx], d = wr3[idx];
            s0 += a.x  * x4.x + a.y  * x4.y + a.z  * x4.z + a.w  * x4.w;
            s1 += bb.x * x4.x + bb.y * x4.y + bb.z * x4.z + bb.w * x4.w;
            s2 += c.x  * x4.x + c.y  * x4.y + c.z  * x4.z + c.w  * x4.w;
            s3 += d.x  * x4.x + d.y  * x4.y + d.z  * x4.z + d.w  * x4.w;
        }
        #pragma unroll
        for (int off = 32; off; off >>= 1) {
            s0 += __shfl_xor(s0, off);
            s1 += __shfl_xor(s1, off);
            s2 += __shfl_xor(s2, off);
            s3 += __shfl_xor(s3, off);
        }
        if (lane == 0) {
            float* op = out + (size_t)b * HIDDEN + r0 + r;
            op[0] = s0; op[1] = s1; op[2] = s2; op[3] = s3;
        }
    }
}

extern "C" void kernel_launch(void* const* d_in, const int* in_sizes, int n_in,
                              void* d_out, int out_size, void* d_ws, size_t ws_size,
                              hipStream_t stream) {
    const float* x        = (const float*)d_in[0];
    const float* position = (const float*)d_in[1];
    const float* kcache   = (const float*)d_in[3];
    const float* vcache   = (const float*)d_in[4];
    const float* wq       = (const float*)d_in[6];
    const float* wk       = (const float*)d_in[7];
    const float* wv       = (const float*)d_in[8];
    const float* wo       = (const float*)d_in[9];
    const float* qnw      = (const float*)d_in[10];
    const float* knw      = (const float*)d_in[11];
    float* ws  = (float*)d_ws;
    float* out = (float*)d_out;

    qkv_kernel<<<32 * 24, 256, 0, stream>>>(x, position, wq, wk, wv, qnw, knw, ws);
    attn_kernel<<<32 * NUM_KV * NSPLIT, 256, 0, stream>>>(kcache, vcache, position, ws);
    comb_kernel<<<32 * NUM_HEADS, 128, 0, stream>>>(ws);
    wo_kernel<<<32 * 16, 256, 0, stream>>>(wo, ws, out);
}

// Round 3
// 218.927 us; speedup vs baseline: 1.4884x; 1.4884x over previous
//
#include <hip/hip_runtime.h>
#include <math.h>

#define MAX_SEQ   1024
#define NUM_HEADS 16
#define NUM_KV    4
#define HEAD_DIM  128
#define HIDDEN    2048
#define GROUPS    4
#define EPS       1e-6f
#define THETA     1000000.0f
#define SCALE     0.08838834764831845f  /* 1/sqrt(128) */
#define NSPLIT    8

// workspace layout (float offsets)
#define QBUF  0                    // 32*16*128 = 65536  (q, post norm+rope)
#define KBUF  65536                // 32*4*128  = 16384  (k_new, post norm+rope)
#define VBUF  81920                // 16384              (v_new)
#define AOUT  98304                // 32*2048 = 65536    (attention output)
#define ARENA 163840               // scratch arena, reused sequentially:
                                   //  (1) qkv partials: 8*32*3072  = 786432
                                   //  (2) attn partials: 1024*4*130 = 532480
                                   //  (3) wo  partials: 16*32*2048 = 1048576
// total ws = 163840 + 1048576 = 1212416 floats = 4.85 MB

// ---------------- batched GEMV tile: 128 rows x 32 batches -----------------
// Weight reuse: each weight element is read by exactly one block.
// LDS stride 68 (=64+4) keeps float4 alignment and spreads banks.
__device__ __forceinline__ void gemv_body(
    const float* __restrict__ W,   // row 0, k-chunk base (row stride 2048)
    const float* __restrict__ X,   // batch 0, k-chunk base (row stride 2048)
    float* __restrict__ part,      // partial out: [32 b][RS rows] for this ksplit
    int RS, int grow0, int nkt)
{
    __shared__ float wt[128 * 68];
    __shared__ float xs[32 * 68];
    const int tid = threadIdx.x, lane = tid & 63, wave = tid >> 6;
    const int rg = tid >> 3, bg = tid & 7;
    const int rrow = wave * 4 + (lane >> 4);
    const int cf = (lane & 15) * 4;

    float acc[4][4];
    #pragma unroll
    for (int i = 0; i < 4; ++i)
        #pragma unroll
        for (int j = 0; j < 4; ++j) acc[i][j] = 0.f;

    for (int kt = 0; kt < nkt; ++kt) {
        const float* Wk = W + kt * 64;
        const float* Xk = X + kt * 64;
        #pragma unroll
        for (int it = 0; it < 8; ++it) {
            const int r = it * 16 + rrow;
            *(float4*)&wt[r * 68 + cf] = *(const float4*)(Wk + (size_t)r * HIDDEN + cf);
        }
        #pragma unroll
        for (int it = 0; it < 2; ++it) {
            const int b = it * 16 + rrow;
            *(float4*)&xs[b * 68 + cf] = *(const float4*)(Xk + (size_t)b * HIDDEN + cf);
        }
        __syncthreads();

        #pragma unroll
        for (int kk = 0; kk < 64; kk += 4) {
            float4 a[4], bb[4];
            #pragma unroll
            for (int i = 0; i < 4; ++i) a[i]  = *(const float4*)&wt[(rg * 4 + i) * 68 + kk];
            #pragma unroll
            for (int j = 0; j < 4; ++j) bb[j] = *(const float4*)&xs[(bg * 4 + j) * 68 + kk];
            #pragma unroll
            for (int i = 0; i < 4; ++i)
                #pragma unroll
                for (int j = 0; j < 4; ++j)
                    acc[i][j] += a[i].x * bb[j].x + a[i].y * bb[j].y
                               + a[i].z * bb[j].z + a[i].w * bb[j].w;
        }
        __syncthreads();
    }

    #pragma unroll
    for (int j = 0; j < 4; ++j) {
        float4 o = make_float4(acc[0][j], acc[1][j], acc[2][j], acc[3][j]);
        *(float4*)(part + (size_t)(bg * 4 + j) * RS + grow0 + rg * 4) = o;
    }
}

// ---------------- Kernel 1a: QKV projection (partials) ---------------------
__global__ __launch_bounds__(256) void gemv_qkv(
    const float* __restrict__ x, const float* __restrict__ wq,
    const float* __restrict__ wk, const float* __restrict__ wv,
    float* __restrict__ ws)
{
    const int mt = blockIdx.x >> 3;          // 0..23 (16 q heads, 4 k, 4 v)
    const int ks = blockIdx.x & 7;           // k-split, chunk = 256
    const float* W;
    if (mt < 16)      W = wq + (size_t)mt * 128 * HIDDEN;
    else if (mt < 20) W = wk + (size_t)(mt - 16) * 128 * HIDDEN;
    else              W = wv + (size_t)(mt - 20) * 128 * HIDDEN;
    const int k0 = ks * 256;
    float* part = ws + ARENA + (size_t)ks * 32 * 3072;
    gemv_body(W + k0, x + k0, part, 3072, mt * 128, 4);
}

// ---------------- Kernel 1b: reduce partials + RMSNorm + RoPE --------------
__global__ __launch_bounds__(128) void qkv_post(
    const float* __restrict__ position, const float* __restrict__ qnw,
    const float* __restrict__ knw, float* __restrict__ ws)
{
    const int blk = blockIdx.x;
    const int b = blk / 24, h = blk % 24;    // h: 0-15 q, 16-19 k, 20-23 v
    const int d = threadIdx.x, lane = d & 63, wave = d >> 6;
    const int grow = h * 128 + d;

    float v = 0.f;
    #pragma unroll
    for (int s = 0; s < NSPLIT; ++s)
        v += ws[ARENA + (size_t)(s * 32 + b) * 3072 + grow];

    if (h >= 20) {                           // v: raw store
        ws[VBUF + (size_t)(b * NUM_KV + (h - 20)) * HEAD_DIM + d] = v;
        return;
    }

    __shared__ float red[2];
    __shared__ float vl[128];
    vl[d] = v;
    float t2 = v * v;
    #pragma unroll
    for (int off = 32; off; off >>= 1) t2 += __shfl_xor(t2, off);
    if (lane == 0) red[wave] = t2;
    __syncthreads();

    if (d < 64) {
        const float norm = rsqrtf((red[0] + red[1]) * (1.0f / HEAD_DIM) + EPS);
        const float* nw = (h < 16) ? qnw : knw;
        float n1 = vl[d]      * norm * nw[d];
        float n2 = vl[d + 64] * norm * nw[d + 64];
        const float p = position[0];
        float invf = __powf(THETA, -(float)d * (1.0f / 64.0f));
        float f = p * invf, s, c;
        __sincosf(f, &s, &c);
        float* outp = (h < 16)
            ? ws + QBUF + (size_t)(b * NUM_HEADS + h) * HEAD_DIM
            : ws + KBUF + (size_t)(b * NUM_KV + (h - 16)) * HEAD_DIM;
        outp[d]      = n1 * c - n2 * s;
        outp[d + 64] = n2 * c + n1 * s;
    }
}

// ---------------- Kernel 2: flash-decode attention (split over seq) --------
__global__ __launch_bounds__(256) void attn_kernel(
    const float* __restrict__ kcache, const float* __restrict__ vcache,
    const float* __restrict__ position, float* __restrict__ ws)
{
    const int blk = blockIdx.x;         // (b*4+kv)*NSPLIT + split
    const int split = blk & (NSPLIT - 1);
    const int bk = blk >> 3;            // b*4+kv
    const int tid = threadIdx.x, lane = tid & 63, wave = tid >> 6;
    const int half = lane >> 5, li = lane & 31;
    const int b = bk >> 2, kv = bk & 3;
    const int pos = (int)position[0];

    const int chunk = (pos + NSPLIT) / NSPLIT;
    const int s0 = split * chunk;
    const int s1 = min(s0 + chunk, pos + 1);

    const float* qb = ws + QBUF + ((size_t)b * NUM_HEADS + kv * GROUPS) * HEAD_DIM;
    float4 q4[4];
    #pragma unroll
    for (int g = 0; g < 4; ++g)
        q4[g] = ((const float4*)(qb + g * HEAD_DIM))[li];

    const float* kc = kcache + (size_t)bk * MAX_SEQ * HEAD_DIM;
    const float* vc = vcache + (size_t)bk * MAX_SEQ * HEAD_DIM;
    const float* knew = ws + KBUF + (size_t)bk * HEAD_DIM;
    const float* vnew = ws + VBUF + (size_t)bk * HEAD_DIM;

    float m[4], l[4]; float4 acc[4];
    #pragma unroll
    for (int g = 0; g < 4; ++g) {
        m[g] = -1e30f; l[g] = 0.f;
        acc[g] = make_float4(0.f, 0.f, 0.f, 0.f);
    }

    for (int t = s0 + wave * 2 + half; t < s1; t += 16) {
        const int tb = t + 8;
        const bool vb = (tb < s1);
        const int tbc = vb ? tb : t;
        const float4* kpa = (const float4*)((t   == pos) ? knew : kc + (size_t)t   * HEAD_DIM);
        const float4* kpb = (const float4*)((tbc == pos) ? knew : kc + (size_t)tbc * HEAD_DIM);
        const float4* vpa = (const float4*)((t   == pos) ? vnew : vc + (size_t)t   * HEAD_DIM);
        const float4* vpb = (const float4*)((tbc == pos) ? vnew : vc + (size_t)tbc * HEAD_DIM);
        float4 ka = kpa[li], kb = kpb[li];
        float4 va = vpa[li], vb4 = vpb[li];

        float sa[4], sb[4];
        #pragma unroll
        for (int g = 0; g < 4; ++g) {
            sa[g] = q4[g].x * ka.x + q4[g].y * ka.y + q4[g].z * ka.z + q4[g].w * ka.w;
            sb[g] = q4[g].x * kb.x + q4[g].y * kb.y + q4[g].z * kb.z + q4[g].w * kb.w;
        }
        #pragma unroll
        for (int off = 16; off; off >>= 1) {
            #pragma unroll
            for (int g = 0; g < 4; ++g) {
                sa[g] += __shfl_xor(sa[g], off);
                sb[g] += __shfl_xor(sb[g], off);
            }
        }
        #pragma unroll
        for (int g = 0; g < 4; ++g) {
            float sga = sa[g] * SCALE;
            float sgb = vb ? sb[g] * SCALE : -1e30f;
            float mn  = fmaxf(m[g], fmaxf(sga, sgb));
            float alpha = __expf(m[g] - mn);
            float pa = __expf(sga - mn);
            float pb = vb ? __expf(sgb - mn) : 0.f;
            l[g] = l[g] * alpha + pa + pb;
            acc[g].x = acc[g].x * alpha + pa * va.x + pb * vb4.x;
            acc[g].y = acc[g].y * alpha + pa * va.y + pb * vb4.y;
            acc[g].z = acc[g].z * alpha + pa * va.z + pb * vb4.z;
            acc[g].w = acc[g].w * alpha + pa * va.w + pb * vb4.w;
            m[g] = mn;
        }
    }

    __shared__ float sm[8][4], sl[8][4];
    __shared__ float4 sacc[8][4][32];
    const int st = wave * 2 + half;
    #pragma unroll
    for (int g = 0; g < 4; ++g) {
        if (li == 0) { sm[st][g] = m[g]; sl[st][g] = l[g]; }
        sacc[st][g][li] = acc[g];
    }
    __syncthreads();

    float* part = ws + ARENA + (size_t)blk * 4 * 130;
    if (tid < HEAD_DIM) {
        const int d = tid;
        #pragma unroll
        for (int g = 0; g < 4; ++g) {
            float M = -1e30f;
            #pragma unroll
            for (int s = 0; s < 8; ++s) M = fmaxf(M, sm[s][g]);
            float L = 0.f, A = 0.f;
            #pragma unroll
            for (int s = 0; s < 8; ++s) {
                float e = __expf(sm[s][g] - M);
                L += sl[s][g] * e;
                A += ((const float*)&sacc[s][g][0])[d] * e;
            }
            part[g * 130 + d] = A;
            if (d == 0) { part[g * 130 + 128] = M; part[g * 130 + 129] = L; }
        }
    }
}

// ---------------- Kernel 3: combine split partials -> attn_out -------------
__global__ __launch_bounds__(128) void comb_kernel(float* __restrict__ ws)
{
    const int blk = blockIdx.x;         // b*16 + h
    const int b = blk >> 4, h = blk & 15;
    const int kv = h >> 2, g = h & 3;
    const int d = threadIdx.x;
    const float* base = ws + ARENA + ((size_t)(b * NUM_KV + kv) * NSPLIT) * 4 * 130 + g * 130;

    float ms[NSPLIT], ls[NSPLIT];
    float M = -1e30f;
    #pragma unroll
    for (int s = 0; s < NSPLIT; ++s) {
        ms[s] = base[s * 520 + 128];
        ls[s] = base[s * 520 + 129];
        M = fmaxf(M, ms[s]);
    }
    float L = 0.f, A = 0.f;
    #pragma unroll
    for (int s = 0; s < NSPLIT; ++s) {
        float e = __expf(ms[s] - M);
        L += ls[s] * e;
        A += base[s * 520 + d] * e;
    }
    ws[AOUT + (size_t)b * HIDDEN + h * HEAD_DIM + d] = A / L;
}

// ---------------- Kernel 4a: output projection (partials) ------------------
__global__ __launch_bounds__(256) void gemv_wo(
    const float* __restrict__ wo, float* __restrict__ ws)
{
    const int mt = blockIdx.x >> 4;          // 0..15 (2048 rows / 128)
    const int ks = blockIdx.x & 15;          // k-split, chunk = 128
    const int k0 = ks * 128;
    float* part = ws + ARENA + (size_t)ks * 32 * 2048;
    gemv_body(wo + (size_t)mt * 128 * HIDDEN + k0, ws + AOUT + k0,
              part, 2048, mt * 128, 2);
}

// ---------------- Kernel 4b: reduce wo partials -> out ---------------------
__global__ __launch_bounds__(256) void ocomb(
    const float* __restrict__ ws, float* __restrict__ out)
{
    const int idx = blockIdx.x * 256 + threadIdx.x;   // 0..16383
    const int b = idx >> 9, r4 = (idx & 511) * 4;
    float4 s = make_float4(0.f, 0.f, 0.f, 0.f);
    #pragma unroll
    for (int k = 0; k < 16; ++k) {
        float4 t = *(const float4*)(ws + ARENA + (size_t)(k * 32 + b) * 2048 + r4);
        s.x += t.x; s.y += t.y; s.z += t.z; s.w += t.w;
    }
    *(float4*)(out + (size_t)b * HIDDEN + r4) = s;
}

extern "C" void kernel_launch(void* const* d_in, const int* in_sizes, int n_in,
                              void* d_out, int out_size, void* d_ws, size_t ws_size,
                              hipStream_t stream) {
    const float* x        = (const float*)d_in[0];
    const float* position = (const float*)d_in[1];
    const float* kcache   = (const float*)d_in[3];
    const float* vcache   = (const float*)d_in[4];
    const float* wq       = (const float*)d_in[6];
    const float* wk       = (const float*)d_in[7];
    const float* wv       = (const float*)d_in[8];
    const float* wo       = (const float*)d_in[9];
    const float* qnw      = (const float*)d_in[10];
    const float* knw      = (const float*)d_in[11];
    float* ws  = (float*)d_ws;
    float* out = (float*)d_out;

    gemv_qkv<<<24 * 8, 256, 0, stream>>>(x, wq, wk, wv, ws);
    qkv_post<<<32 * 24, 128, 0, stream>>>(position, qnw, knw, ws);
    attn_kernel<<<32 * NUM_KV * NSPLIT, 256, 0, stream>>>(kcache, vcache, position, ws);
    comb_kernel<<<32 * NUM_HEADS, 128, 0, stream>>>(ws);
    gemv_wo<<<16 * 16, 256, 0, stream>>>(wo, ws);
    ocomb<<<64, 256, 0, stream>>>(ws, out);
}